// Round 18
// baseline (250.943 us; speedup 1.0000x reference)
//
#include <hip/hip_runtime.h>
#include <hip/hip_bf16.h>
#include <stdint.h>

#define DD 2048
#define SS 2048
#define NB 2
#define NH 16
#define HDIM 128
#define MM (NB*SS)   // 4096 rows

typedef __attribute__((ext_vector_type(8))) short bf16x8;
typedef __attribute__((ext_vector_type(4))) float f32x4;
typedef __attribute__((ext_vector_type(4))) ushort u16x4;

__device__ __forceinline__ float fast_exp2(float x) {
  return __builtin_amdgcn_exp2f(x);   // v_exp_f32 (2^x natively)
}

// RTNE f32->bf16 via compiler cast: emits v_cvt_pk_bf16_f32 (m240: scalar
// casts fuse; hand-rolled add/shift bit math does not).
__device__ __forceinline__ ushort f2bf(float f) {
  union { __hip_bfloat16 h; ushort u; } v;
  v.h = __float2bfloat16(f);
  return v.u;
}

__device__ __forceinline__ void gld_lds16(const ushort* g, ushort* l) {
  __builtin_amdgcn_global_load_lds(
      (const __attribute__((address_space(1))) void*)g,
      (__attribute__((address_space(3))) void*)l, 16, 0, 0);
}

// ------- fp32 -> bf16 conversion: grid-stride, 2048 blocks, 64B/thread ------
__global__ __launch_bounds__(256) void cvt_all(
    const float* __restrict__ x, const float* __restrict__ wq,
    const float* __restrict__ wk, const float* __restrict__ wv,
    const float* __restrict__ wo, ushort* __restrict__ dst)
{
  const int X8 = MM * DD / 8;                // 1,048,576
  const int W8 = DD * DD / 8;                // 524,288
  const int TOT8 = X8 + 4*W8;                // 3,145,728 8-float chunks
  for (int i8 = blockIdx.x * 256 + threadIdx.x; i8 < TOT8;
       i8 += gridDim.x * 256) {
    const float* src; int off;
    if (i8 < X8)            { src = x;  off = i8; }
    else if (i8 < X8 +   W8){ src = wq; off = i8 - X8; }
    else if (i8 < X8 + 2*W8){ src = wk; off = i8 - (X8 +   W8); }
    else if (i8 < X8 + 3*W8){ src = wv; off = i8 - (X8 + 2*W8); }
    else                    { src = wo; off = i8 - (X8 + 3*W8); }
    const float4* p = (const float4*)src;
    float4 a = p[(long)off*2], b = p[(long)off*2 + 1];
    bf16x8 o;
    o[0]=(short)f2bf(a.x); o[1]=(short)f2bf(a.y); o[2]=(short)f2bf(a.z); o[3]=(short)f2bf(a.w);
    o[4]=(short)f2bf(b.x); o[5]=(short)f2bf(b.y); o[6]=(short)f2bf(b.z); o[7]=(short)f2bf(b.w);
    *(bf16x8*)(dst + (long)i8*8) = o;
  }
}

// ---- QKV GEMM: 256x128 tile, BK=32, 4 waves, TRIPLE buffer (R12-verified) ---
__global__ __launch_bounds__(256, 2) void gemm_qkv(
    const ushort* __restrict__ A, const ushort* __restrict__ Bt,
    ushort* __restrict__ Qo, ushort* __restrict__ Ko, ushort* __restrict__ Vt)
{
  __shared__ ushort lds[3 * 12288];          // 3 x 24 KB = 72 KB
  const int t = threadIdx.x;
  const int bid = blockIdx.x;
  const int xcd = bid & 7, local = bid >> 3;
  const int NBX = 6;
  const int bm = local / NBX;
  const int bn = xcd * NBX + (local - bm * NBX);
  const int lane = t & 63, w = t >> 6;       // 4 waves
  const int wr = w >> 1, wcn = w & 1;        // 2M x 2N; per-wave 128x64
  const int lr = lane & 15, lg = lane >> 4;  // lg 0..3

  int aoff[4], boff[2];
#pragma unroll
  for (int i = 0; i < 4; ++i) {
    int p = i*256 + t, ln = p >> 3, sr = (p & 7) ^ (ln & 7);
    aoff[i] = (2*ln + (sr >> 2)) * DD + (sr & 3) * 8;
  }
#pragma unroll
  for (int i = 0; i < 2; ++i) {
    int p = i*256 + t, ln = p >> 3, sr = (p & 7) ^ (ln & 7);
    boff[i] = (2*ln + (sr >> 2)) * DD + (sr & 3) * 8;
  }
  const ushort* Ab = A  + (long)(bm*256) * DD;
  const ushort* Bb = Bt + (long)(bn*128) * DD;

#define STG_A01(KT, BUF) do { const ushort* g_ = Ab + (KT)*32;             \
    ushort* l_ = lds + (BUF)*12288;                                        \
    gld_lds16(g_ + aoff[0], l_ + t*8);                                     \
    gld_lds16(g_ + aoff[1], l_ + (256 + t)*8); } while (0)
#define STG_A23(KT, BUF) do { const ushort* g_ = Ab + (KT)*32;             \
    ushort* l_ = lds + (BUF)*12288;                                        \
    gld_lds16(g_ + aoff[2], l_ + (512 + t)*8);                             \
    gld_lds16(g_ + aoff[3], l_ + (768 + t)*8); } while (0)
#define STG_B(KT, BUF)   do { const ushort* g_ = Bb + (KT)*32;             \
    ushort* l_ = lds + (BUF)*12288 + 8192;                                 \
    gld_lds16(g_ + boff[0], l_ + t*8);                                     \
    gld_lds16(g_ + boff[1], l_ + (256 + t)*8); } while (0)
#define LDA(dst, m) { int r_ = wr*128 + (m)*16 + lr; int ln_ = r_ >> 1;    \
    int sl_ = (lg + ((r_ & 1) << 2)) ^ (ln_ & 7);                          \
    (dst) = *(const bf16x8*)(cb + ln_*128 + sl_*16); }
#define LDB(dst, n) { int r_ = wcn*64 + (n)*16 + lr; int ln_ = r_ >> 1;    \
    int sl_ = (lg + ((r_ & 1) << 2)) ^ (ln_ & 7);                          \
    (dst) = *(const bf16x8*)(cb + 16384 + ln_*128 + sl_*16); }
#define MFMA42(AV, BV, MB, NB_) do {                                       \
    __builtin_amdgcn_s_setprio(1);                                         \
    _Pragma("unroll") for (int m = 0; m < 4; ++m)                          \
    _Pragma("unroll") for (int n = 0; n < 2; ++n)                          \
      acc[(MB)+m][(NB_)+n] = __builtin_amdgcn_mfma_f32_16x16x32_bf16(      \
          AV[m], BV[n], acc[(MB)+m][(NB_)+n], 0, 0, 0);                    \
    __builtin_amdgcn_s_setprio(0); } while (0)
#define SB  __builtin_amdgcn_sched_barrier(0)
#define BAR __builtin_amdgcn_s_barrier()
#define LGKM0 asm volatile("s_waitcnt lgkmcnt(0)" ::: "memory")

  f32x4 acc[8][4] = {};
  const int T = DD / 32;                     // 64 K-tiles

  STG_A01(0, 0); STG_A23(0, 0); STG_B(0, 0);
  STG_A01(1, 1); STG_A23(1, 1); STG_B(1, 1);
  asm volatile("s_waitcnt vmcnt(6)" ::: "memory");
  SB; BAR; SB;

  for (int kt = 0; kt < T; ++kt) {
    const char* cb = (const char*)lds + (kt % 3) * 24576;
    const int bs = (kt + 2) % 3;
    const bool st = (kt + 2 < T);
    bf16x8 a03[4], a47[4], b01[2], b23[2];
    LDA(a03[0],0); LDA(a03[1],1); LDA(a03[2],2); LDA(a03[3],3);
    LDB(b01[0],0); LDB(b01[1],1);
    if (st) STG_A01(kt+2, bs);
    SB; BAR; LGKM0; SB;
    MFMA42(a03, b01, 0, 0);
    SB; BAR; SB;
    LDA(a47[0],4); LDA(a47[1],5); LDA(a47[2],6); LDA(a47[3],7);
    if (st) STG_A23(kt+2, bs);
    SB; BAR; LGKM0; SB;
    MFMA42(a47, b01, 4, 0);
    SB; BAR; SB;
    LDB(b23[0],2); LDB(b23[1],3);
    if (st) STG_B(kt+2, bs);
    SB; BAR; LGKM0; SB;
    MFMA42(a03, b23, 0, 2);
    SB; BAR; SB;
    if (st)              { asm volatile("s_waitcnt vmcnt(6)" ::: "memory"); }
    else if (kt + 1 < T) { asm volatile("s_waitcnt vmcnt(0)" ::: "memory"); }
    SB; BAR; SB;
    MFMA42(a47, b23, 4, 2);
    SB; BAR; SB;
  }
#undef STG_A01
#undef STG_A23
#undef STG_B
#undef LDA
#undef LDB
#undef MFMA42

  const int crb = bm*256 + wr*128 + lg*4;
  const int region = bn >> 4;              // 0=Q, 1=K, 2=V (16 bn each)
  const int ccb = (bn & 15)*128 + wcn*64 + lr;
  if (region < 2) {
    const float scale = (region == 0) ? (0.08838834764831845f * 1.4426950408889634f) : 1.0f;
    ushort* C = (region == 0) ? Qo : Ko;
#pragma unroll
    for (int m = 0; m < 8; ++m)
#pragma unroll
      for (int n = 0; n < 4; ++n)
#pragma unroll
        for (int j = 0; j < 4; ++j)
          C[(long)(crb + m*16 + j) * DD + (ccb + n*16)] = f2bf(acc[m][n][j] * scale);
  } else {
#pragma unroll
    for (int m = 0; m < 8; ++m) {
      int sg = crb + m*16;
      int b2 = sg >> 11, s2 = sg & 2047;
#pragma unroll
      for (int n = 0; n < 4; ++n) {
        int colv = ccb + n*16;
        int h2 = colv >> 7, d2 = colv & 127;
        u16x4 pk;
        pk[0] = f2bf(acc[m][n][0]); pk[1] = f2bf(acc[m][n][1]);
        pk[2] = f2bf(acc[m][n][2]); pk[3] = f2bf(acc[m][n][3]);
        *(u16x4*)(Vt + ((long)((b2*NH + h2)*HDIM + d2)) * SS + s2) = pk;
      }
    }
  }
#undef SB
#undef BAR
#undef LGKM0
}

// ---- O-proj GEMM: 128x128 tile, BK=32, 4 waves (each 64x64), TRIPLE buf ----
__global__ __launch_bounds__(256, 3) void gemm_o128(
    const ushort* __restrict__ A, const ushort* __restrict__ Bt,
    float* __restrict__ Cf)
{
  __shared__ ushort lds[3 * 8192];           // 3 x 16 KB = 48 KB
  const int t = threadIdx.x;
  const int bid = blockIdx.x;                // 512 = 8 XCD x 64
  const int xcd = bid & 7, local = bid >> 3;
  const int bm = local >> 1;                 // 0..31
  const int bn = xcd * 2 + (local & 1);      // 0..15
  const int lane = t & 63, w = t >> 6;       // 4 waves, 2x2
  const int wr = w >> 1, wcn = w & 1;        // per-wave 64x64
  const int lr = lane & 15, lg = lane >> 4;

  int aoff[2], boff[2];
#pragma unroll
  for (int i = 0; i < 2; ++i) {
    int p = i*256 + t, ln = p >> 3, sr = (p & 7) ^ (ln & 7);
    aoff[i] = (2*ln + (sr >> 2)) * DD + (sr & 3) * 8;
    boff[i] = aoff[i];
  }
  const ushort* Ab = A  + (long)(bm*128) * DD;
  const ushort* Bb = Bt + (long)(bn*128) * DD;

#define STG_A(KT, BUF) do { const ushort* g_ = Ab + (KT)*32;               \
    ushort* l_ = lds + (BUF)*8192;                                         \
    gld_lds16(g_ + aoff[0], l_ + t*8);                                     \
    gld_lds16(g_ + aoff[1], l_ + (256 + t)*8); } while (0)
#define STG_B(KT, BUF) do { const ushort* g_ = Bb + (KT)*32;               \
    ushort* l_ = lds + (BUF)*8192 + 4096;                                  \
    gld_lds16(g_ + boff[0], l_ + t*8);                                     \
    gld_lds16(g_ + boff[1], l_ + (256 + t)*8); } while (0)
#define LDA(dst, m) { int r_ = wr*64 + (m)*16 + lr; int ln_ = r_ >> 1;     \
    int sl_ = (lg + ((r_ & 1) << 2)) ^ (ln_ & 7);                          \
    (dst) = *(const bf16x8*)(cb + ln_*128 + sl_*16); }
#define LDB(dst, n) { int r_ = wcn*64 + (n)*16 + lr; int ln_ = r_ >> 1;    \
    int sl_ = (lg + ((r_ & 1) << 2)) ^ (ln_ & 7);                          \
    (dst) = *(const bf16x8*)(cb + 8192 + ln_*128 + sl_*16); }
#define MFMA8(AV, BV, NB_) do {                                            \
    __builtin_amdgcn_s_setprio(1);                                         \
    _Pragma("unroll") for (int m = 0; m < 4; ++m)                          \
    _Pragma("unroll") for (int n = 0; n < 2; ++n)                          \
      acc[m][(NB_)+n] = __builtin_amdgcn_mfma_f32_16x16x32_bf16(           \
          AV[m], BV[n], acc[m][(NB_)+n], 0, 0, 0);                         \
    __builtin_amdgcn_s_setprio(0); } while (0)
#define SB  __builtin_amdgcn_sched_barrier(0)
#define BAR __builtin_amdgcn_s_barrier()
#define LGKM0 asm volatile("s_waitcnt lgkmcnt(0)" ::: "memory")

  f32x4 acc[4][4] = {};
  const int T = DD / 32;                     // 64 K-tiles

  STG_A(0, 0); STG_B(0, 0);
  STG_A(1, 1); STG_B(1, 1);
  asm volatile("s_waitcnt vmcnt(4)" ::: "memory");
  SB; BAR; SB;

  for (int kt = 0; kt < T; ++kt) {
    const char* cb = (const char*)lds + (kt % 3) * 16384;
    const int bs = (kt + 2) % 3;
    const bool st = (kt + 2 < T);
    bf16x8 a[4], b01[2], b23[2];
    LDA(a[0],0); LDA(a[1],1); LDA(a[2],2); LDA(a[3],3);
    LDB(b01[0],0); LDB(b01[1],1);
    if (st) STG_A(kt+2, bs);
    SB; BAR; LGKM0; SB;
    MFMA8(a, b01, 0);
    SB; BAR; SB;
    LDB(b23[0],2); LDB(b23[1],3);
    if (st) STG_B(kt+2, bs);
    SB; BAR; LGKM0; SB;
    MFMA8(a, b23, 2);
    SB;
    if (st)              { asm volatile("s_waitcnt vmcnt(4)" ::: "memory"); }
    else if (kt + 1 < T) { asm volatile("s_waitcnt vmcnt(0)" ::: "memory"); }
    SB; BAR; SB;
  }
#undef STG_A
#undef STG_B
#undef LDA
#undef LDB
#undef MFMA8
#undef SB
#undef BAR
#undef LGKM0

  const int crb = bm*128 + wr*64 + lg*4;
  const int ccb = bn*128 + wcn*64 + lr;
#pragma unroll
  for (int m = 0; m < 4; ++m)
#pragma unroll
    for (int n = 0; n < 4; ++n)
#pragma unroll
      for (int j = 0; j < 4; ++j)
        Cf[(long)(crb + m*16 + j) * DD + (ccb + n*16)] = acc[m][n][j];
}

// ------ causal flash attention: KVBLK=128, dbuf, pair-balance, defer-max -----
__global__ __launch_bounds__(512, 2) void attn_fwd(
    const ushort* __restrict__ Qb, const ushort* __restrict__ Kb,
    const ushort* __restrict__ Vtg, ushort* __restrict__ Ob)
{
  __shared__ ushort Ks[2][128*128]; // 2 x 32 KB, [k][d] rows 256B swizzled
  __shared__ ushort Vs[2][128*128]; // 2 x 32 KB, [d][s] rows 256B swizzled
  __shared__ ushort Ps[8*16*68];    // per-wave P [16][64], pad 68 (2-way)

  const int bid = blockIdx.x;       // 256 blocks: p(8) x bh(32)
  const int p = bid >> 5;           // 0..7
  const int bh = bid & 31;
  const int b = bh >> 4, h = bh & 15;
  const int t = threadIdx.x;
  const int lane = t & 63;
  const int wq = t >> 6;            // 0..7
  const int lr = lane & 15, lg = lane >> 4;

  int koff[4], voff[4];
#pragma unroll
  for (int i = 0; i < 4; ++i) {
    int c = i*512 + t;
    int kr = c >> 4, kc = c & 15;
    koff[i] = kr*DD + ((kc ^ (kr & 7)) * 8);
    voff[i] = kr*SS + ((kc ^ (kr & 7)) * 8);
  }
  const ushort* Kg = Kb + (long)(b * SS) * DD + h * HDIM;
  const ushort* Vg = Vtg + (long)(bh * HDIM) * SS;

#define STAGE(KT, BUF) do {                                     \
    const ushort* kg_ = Kg + (long)(KT) * 128 * DD;             \
    const ushort* vg_ = Vg + (KT) * 128;                        \
    _Pragma("unroll") for (int i_ = 0; i_ < 4; ++i_) {          \
      gld_lds16(kg_ + koff[i_], &Ks[BUF][i_*4096 + t*8]);       \
      gld_lds16(vg_ + voff[i_], &Vs[BUF][i_*4096 + t*8]);       \
    } } while (0)

  ushort* myP = Ps + wq * (16*68);
  const int n0 = p + 1;             // half-0 tile count (128-key tiles)
  const int TOT = 17;               // n0 + (16 - p)

  STAGE(0, 0);
  __syncthreads();                  // tile 0 resident

  int u = 0;
  for (int half = 0; half < 2; ++half) {
    const int qt = half ? (15 - p) : p;
    const int qbase = qt * 128;
    const long rowQ = (long)(b * SS + qbase + wq * 16);
    const int ntile = qt + 1;
    const int qminw = qbase + wq*16;

    bf16x8 qf[4];
#pragma unroll
    for (int c = 0; c < 4; ++c)
      qf[c] = *(const bf16x8*)(Qb + (rowQ + lr) * DD + h*HDIM + c*32 + lg*8);

    f32x4 accO[8] = {};
    float mrow[4], lrow[4];
#pragma unroll
    for (int j = 0; j < 4; ++j) { mrow[j] = -1e30f; lrow[j] = 0.f; }

    for (int kt = 0; kt < ntile; ++kt, ++u) {
      const int k0 = kt * 128;
      const int cur = u & 1;
      if (u + 1 < TOT) {
        const int un = u + 1;
        const int ktn = (un < n0) ? un : un - n0;
        STAGE(ktn, cur ^ 1);
      }

      const ushort* Kc = Ks[cur];
      const ushort* Vc = Vs[cur];
      f32x4 sc[8] = {};
      __builtin_amdgcn_s_setprio(1);
#pragma unroll
      for (int n = 0; n < 8; ++n) { // S = Q K^T : 16 q-rows x 128 keys
        int r = n*16 + lr;
        int swz = (r & 7) << 4;
#pragma unroll
        for (int c = 0; c < 4; ++c) {
          bf16x8 kf = *(const bf16x8*)((const char*)Kc + ((r*256 + c*64 + lg*16) ^ swz));
          sc[n] = __builtin_amdgcn_mfma_f32_16x16x32_bf16(qf[c], kf, sc[n], 0,0,0);
        }
      }
      __builtin_amdgcn_s_setprio(0);
      if (kt == ntile - 1) {        // diagonal 128-tile: causal mask
#pragma unroll
        for (int n = 0; n < 8; ++n)
#pragma unroll
          for (int j = 0; j < 4; ++j) {
            int kpos = k0 + n*16 + lr;
            int qpos = qminw + lg*4 + j;
            if (kpos > qpos) sc[n][j] = -1e30f;
          }
      }
      // tile max per row + defer-max decision (T13)
      float tm[4]; float gd = -1e30f;
#pragma unroll
      for (int j = 0; j < 4; ++j) {
        float m8 = fmaxf(fmaxf(fmaxf(sc[0][j], sc[1][j]), fmaxf(sc[2][j], sc[3][j])),
                         fmaxf(fmaxf(sc[4][j], sc[5][j]), fmaxf(sc[6][j], sc[7][j])));
#pragma unroll
        for (int off = 1; off < 16; off <<= 1) m8 = fmaxf(m8, __shfl_xor(m8, off));
        tm[j] = m8;
        gd = fmaxf(gd, m8 - mrow[j]);
      }
      const bool resc = !__all(gd <= 8.0f);
      float al[4];
      if (resc) {
#pragma unroll
        for (int j = 0; j < 4; ++j) {
          float mn = fmaxf(mrow[j], tm[j]);
          al[j] = fast_exp2(mrow[j] - mn);
          mrow[j] = mn;
        }
#pragma unroll
        for (int dg = 0; dg < 8; ++dg) {
          f32x4 v = accO[dg];
          v[0] *= al[0]; v[1] *= al[1]; v[2] *= al[2]; v[3] *= al[3];
          accO[dg] = v;
        }
      }
#pragma unroll
      for (int j = 0; j < 4; ++j) { // P = exp2(S - mrow); row-sum
        float ts = 0.f;
#pragma unroll
        for (int n = 0; n < 8; ++n) {
          float pv = fast_exp2(sc[n][j] - mrow[j]);
          sc[n][j] = pv; ts += pv;
        }
#pragma unroll
        for (int off = 1; off < 16; off <<= 1) ts += __shfl_xor(ts, off);
        lrow[j] = (resc ? lrow[j] * al[j] : lrow[j]) + ts;
      }
      // PV in two 64-key halves (P buffer is 16x64 per wave)
#pragma unroll
      for (int hh = 0; hh < 2; ++hh) {
#pragma unroll
        for (int n2 = 0; n2 < 4; ++n2)
#pragma unroll
          for (int j = 0; j < 4; ++j)
            myP[(lg*4 + j)*68 + n2*16 + lr] = f2bf(sc[hh*4 + n2][j]);
        bf16x8 pa0 = *(const bf16x8*)(myP + lr*68 + lg*8);
        bf16x8 pa1 = *(const bf16x8*)(myP + lr*68 + 32 + lg*8);
        __builtin_amdgcn_s_setprio(1);
#pragma unroll
        for (int dg = 0; dg < 8; ++dg) { // O += P_half * V_half
          int d = dg*16 + lr;
          int vswz = (d & 7) << 4;
          bf16x8 v0 = *(const bf16x8*)((const char*)Vc + ((d*256 + hh*128 + lg*16) ^ vswz));
          bf16x8 v1 = *(const bf16x8*)((const char*)Vc + ((d*256 + hh*128 + 64 + lg*16) ^ vswz));
          accO[dg] = __builtin_amdgcn_mfma_f32_16x16x32_bf16(pa0, v0, accO[dg], 0,0,0);
          accO[dg] = __builtin_amdgcn_mfma_f32_16x16x32_bf16(pa1, v1, accO[dg], 0,0,0);
        }
        __builtin_amdgcn_s_setprio(0);
      }
      __syncthreads();              // drains next tile's loads (after compute)
    }

    float inv[4];
#pragma unroll
    for (int j = 0; j < 4; ++j) inv[j] = 1.0f / lrow[j];
    ushort* Og = Ob + rowQ * DD + h * HDIM;
#pragma unroll
    for (int dg = 0; dg < 8; ++dg)
#pragma unroll
      for (int j = 0; j < 4; ++j)
        Og[(long)(lg*4 + j) * DD + dg*16 + lr] = f2bf(accO[dg][j] * inv[j]);
  }
#undef STAGE
}

// ---------------- launch ----------------------------------------------------
extern "C" void kernel_launch(void* const* d_in, const int* in_sizes, int n_in,
                              void* d_out, int out_size, void* d_ws, size_t ws_size,
                              hipStream_t stream) {
  const float* x  = (const float*)d_in[0];
  const float* Wq = (const float*)d_in[1];
  const float* Wk = (const float*)d_in[2];
  const float* Wv = (const float*)d_in[3];
  const float* Wo = (const float*)d_in[4];

  ushort* ws  = (ushort*)d_ws;
  ushort* xb  = ws;                         // x bf16; later reused as attn-out
  ushort* wqb = ws  + (long)MM*DD;          // wq/wk/wv contiguous = fused Bt
  ushort* wkb = wqb + (long)DD*DD;
  ushort* wvb = wkb + (long)DD*DD;
  ushort* wob = wvb + (long)DD*DD;
  ushort* Qb  = wob + (long)DD*DD;
  ushort* Kb  = Qb  + (long)MM*DD;
  ushort* Vtg = Kb  + (long)MM*DD;          // V stored transposed [bh*128+d][s]
  (void)wkb; (void)wvb;

  cvt_all<<<2048, 256, 0, stream>>>(x, Wq, Wk, Wv, Wo, ws);

  gemm_qkv<<<768, 256, 0, stream>>>(xb, wqb, Qb, Kb, Vtg);

  attn_fwd<<<256, 512, 0, stream>>>(Qb, Kb, Vtg, xb);   // attn out -> xb

  gemm_o128<<<512, 256, 0, stream>>>(xb, wob, (float*)d_out);
}

// Round 19
// 244.100 us; speedup vs baseline: 1.0280x; 1.0280x over previous
//
#include <hip/hip_runtime.h>
#include <hip/hip_bf16.h>
#include <stdint.h>

#define DD 2048
#define SS 2048
#define NB 2
#define NH 16
#define HDIM 128
#define MM (NB*SS)   // 4096 rows

typedef __attribute__((ext_vector_type(8))) short bf16x8;
typedef __attribute__((ext_vector_type(4))) float f32x4;
typedef __attribute__((ext_vector_type(4))) ushort u16x4;

__device__ __forceinline__ float fast_exp2(float x) {
  return __builtin_amdgcn_exp2f(x);   // v_exp_f32 (2^x natively)
}

__device__ __forceinline__ ushort f2bf(float f) {
  union { __hip_bfloat16 h; ushort u; } v;
  v.h = __float2bfloat16(f);
  return v.u;
}

__device__ __forceinline__ void gld_lds16(const ushort* g, ushort* l) {
  __builtin_amdgcn_global_load_lds(
      (const __attribute__((address_space(1))) void*)g,
      (__attribute__((address_space(3))) void*)l, 16, 0, 0);
}

// ------- fp32 -> bf16 conversion: grid-stride, 2048 blocks, 64B/thread ------
__global__ __launch_bounds__(256) void cvt_all(
    const float* __restrict__ x, const float* __restrict__ wq,
    const float* __restrict__ wk, const float* __restrict__ wv,
    const float* __restrict__ wo, ushort* __restrict__ dst)
{
  const int X8 = MM * DD / 8;                // 1,048,576
  const int W8 = DD * DD / 8;                // 524,288
  const int TOT8 = X8 + 4*W8;                // 3,145,728 8-float chunks
  for (int i8 = blockIdx.x * 256 + threadIdx.x; i8 < TOT8;
       i8 += gridDim.x * 256) {
    const float* src; int off;
    if (i8 < X8)            { src = x;  off = i8; }
    else if (i8 < X8 +   W8){ src = wq; off = i8 - X8; }
    else if (i8 < X8 + 2*W8){ src = wk; off = i8 - (X8 +   W8); }
    else if (i8 < X8 + 3*W8){ src = wv; off = i8 - (X8 + 2*W8); }
    else                    { src = wo; off = i8 - (X8 + 3*W8); }
    const float4* p = (const float4*)src;
    float4 a = p[(long)off*2], b = p[(long)off*2 + 1];
    bf16x8 o;
    o[0]=(short)f2bf(a.x); o[1]=(short)f2bf(a.y); o[2]=(short)f2bf(a.z); o[3]=(short)f2bf(a.w);
    o[4]=(short)f2bf(b.x); o[5]=(short)f2bf(b.y); o[6]=(short)f2bf(b.z); o[7]=(short)f2bf(b.w);
    *(bf16x8*)(dst + (long)i8*8) = o;
  }
}

// ---- QKV GEMM: 256x128 tile, BK=32, 4 waves, TRIPLE buffer (R12-verified) ---
__global__ __launch_bounds__(256, 2) void gemm_qkv(
    const ushort* __restrict__ A, const ushort* __restrict__ Bt,
    ushort* __restrict__ Qo, ushort* __restrict__ Ko, ushort* __restrict__ Vt)
{
  __shared__ ushort lds[3 * 12288];          // 3 x 24 KB = 72 KB
  const int t = threadIdx.x;
  const int bid = blockIdx.x;
  const int xcd = bid & 7, local = bid >> 3;
  const int NBX = 6;
  const int bm = local / NBX;
  const int bn = xcd * NBX + (local - bm * NBX);
  const int lane = t & 63, w = t >> 6;       // 4 waves
  const int wr = w >> 1, wcn = w & 1;        // 2M x 2N; per-wave 128x64
  const int lr = lane & 15, lg = lane >> 4;  // lg 0..3

  int aoff[4], boff[2];
#pragma unroll
  for (int i = 0; i < 4; ++i) {
    int p = i*256 + t, ln = p >> 3, sr = (p & 7) ^ (ln & 7);
    aoff[i] = (2*ln + (sr >> 2)) * DD + (sr & 3) * 8;
  }
#pragma unroll
  for (int i = 0; i < 2; ++i) {
    int p = i*256 + t, ln = p >> 3, sr = (p & 7) ^ (ln & 7);
    boff[i] = (2*ln + (sr >> 2)) * DD + (sr & 3) * 8;
  }
  const ushort* Ab = A  + (long)(bm*256) * DD;
  const ushort* Bb = Bt + (long)(bn*128) * DD;

#define STG_A01(KT, BUF) do { const ushort* g_ = Ab + (KT)*32;             \
    ushort* l_ = lds + (BUF)*12288;                                        \
    gld_lds16(g_ + aoff[0], l_ + t*8);                                     \
    gld_lds16(g_ + aoff[1], l_ + (256 + t)*8); } while (0)
#define STG_A23(KT, BUF) do { const ushort* g_ = Ab + (KT)*32;             \
    ushort* l_ = lds + (BUF)*12288;                                        \
    gld_lds16(g_ + aoff[2], l_ + (512 + t)*8);                             \
    gld_lds16(g_ + aoff[3], l_ + (768 + t)*8); } while (0)
#define STG_B(KT, BUF)   do { const ushort* g_ = Bb + (KT)*32;             \
    ushort* l_ = lds + (BUF)*12288 + 8192;                                 \
    gld_lds16(g_ + boff[0], l_ + t*8);                                     \
    gld_lds16(g_ + boff[1], l_ + (256 + t)*8); } while (0)
#define LDA(dst, m) { int r_ = wr*128 + (m)*16 + lr; int ln_ = r_ >> 1;    \
    int sl_ = (lg + ((r_ & 1) << 2)) ^ (ln_ & 7);                          \
    (dst) = *(const bf16x8*)(cb + ln_*128 + sl_*16); }
#define LDB(dst, n) { int r_ = wcn*64 + (n)*16 + lr; int ln_ = r_ >> 1;    \
    int sl_ = (lg + ((r_ & 1) << 2)) ^ (ln_ & 7);                          \
    (dst) = *(const bf16x8*)(cb + 16384 + ln_*128 + sl_*16); }
#define MFMA42(AV, BV, MB, NB_) do {                                       \
    __builtin_amdgcn_s_setprio(1);                                         \
    _Pragma("unroll") for (int m = 0; m < 4; ++m)                          \
    _Pragma("unroll") for (int n = 0; n < 2; ++n)                          \
      acc[(MB)+m][(NB_)+n] = __builtin_amdgcn_mfma_f32_16x16x32_bf16(      \
          AV[m], BV[n], acc[(MB)+m][(NB_)+n], 0, 0, 0);                    \
    __builtin_amdgcn_s_setprio(0); } while (0)
#define SB  __builtin_amdgcn_sched_barrier(0)
#define BAR __builtin_amdgcn_s_barrier()
#define LGKM0 asm volatile("s_waitcnt lgkmcnt(0)" ::: "memory")

  f32x4 acc[8][4] = {};
  const int T = DD / 32;                     // 64 K-tiles

  STG_A01(0, 0); STG_A23(0, 0); STG_B(0, 0);
  STG_A01(1, 1); STG_A23(1, 1); STG_B(1, 1);
  asm volatile("s_waitcnt vmcnt(6)" ::: "memory");
  SB; BAR; SB;

  for (int kt = 0; kt < T; ++kt) {
    const char* cb = (const char*)lds + (kt % 3) * 24576;
    const int bs = (kt + 2) % 3;
    const bool st = (kt + 2 < T);
    bf16x8 a03[4], a47[4], b01[2], b23[2];
    LDA(a03[0],0); LDA(a03[1],1); LDA(a03[2],2); LDA(a03[3],3);
    LDB(b01[0],0); LDB(b01[1],1);
    if (st) STG_A01(kt+2, bs);
    SB; BAR; LGKM0; SB;
    MFMA42(a03, b01, 0, 0);
    SB; BAR; SB;
    LDA(a47[0],4); LDA(a47[1],5); LDA(a47[2],6); LDA(a47[3],7);
    if (st) STG_A23(kt+2, bs);
    SB; BAR; LGKM0; SB;
    MFMA42(a47, b01, 4, 0);
    SB; BAR; SB;
    LDB(b23[0],2); LDB(b23[1],3);
    if (st) STG_B(kt+2, bs);
    SB; BAR; LGKM0; SB;
    MFMA42(a03, b23, 0, 2);
    SB; BAR; SB;
    if (st)              { asm volatile("s_waitcnt vmcnt(6)" ::: "memory"); }
    else if (kt + 1 < T) { asm volatile("s_waitcnt vmcnt(0)" ::: "memory"); }
    SB; BAR; SB;
    MFMA42(a47, b23, 4, 2);
    SB; BAR; SB;
  }
#undef STG_A01
#undef STG_A23
#undef STG_B
#undef LDA
#undef LDB
#undef MFMA42

  const int crb = bm*256 + wr*128 + lg*4;
  const int region = bn >> 4;              // 0=Q, 1=K, 2=V (16 bn each)
  const int ccb = (bn & 15)*128 + wcn*64 + lr;
  if (region < 2) {
    const float scale = (region == 0) ? (0.08838834764831845f * 1.4426950408889634f) : 1.0f;
    ushort* C = (region == 0) ? Qo : Ko;
#pragma unroll
    for (int m = 0; m < 8; ++m)
#pragma unroll
      for (int n = 0; n < 4; ++n)
#pragma unroll
        for (int j = 0; j < 4; ++j)
          C[(long)(crb + m*16 + j) * DD + (ccb + n*16)] = f2bf(acc[m][n][j] * scale);
  } else {
#pragma unroll
    for (int m = 0; m < 8; ++m) {
      int sg = crb + m*16;
      int b2 = sg >> 11, s2 = sg & 2047;
#pragma unroll
      for (int n = 0; n < 4; ++n) {
        int colv = ccb + n*16;
        int h2 = colv >> 7, d2 = colv & 127;
        u16x4 pk;
        pk[0] = f2bf(acc[m][n][0]); pk[1] = f2bf(acc[m][n][1]);
        pk[2] = f2bf(acc[m][n][2]); pk[3] = f2bf(acc[m][n][3]);
        *(u16x4*)(Vt + ((long)((b2*NH + h2)*HDIM + d2)) * SS + s2) = pk;
      }
    }
  }
#undef SB
#undef BAR
#undef LGKM0
}

// ---- O-proj GEMM: 128x128 tile, BK=32, 4 waves (each 64x64), TRIPLE buf ----
__global__ __launch_bounds__(256, 3) void gemm_o128(
    const ushort* __restrict__ A, const ushort* __restrict__ Bt,
    float* __restrict__ Cf)
{
  __shared__ ushort lds[3 * 8192];           // 3 x 16 KB = 48 KB
  const int t = threadIdx.x;
  const int bid = blockIdx.x;                // 512 = 8 XCD x 64
  const int xcd = bid & 7, local = bid >> 3;
  const int bm = local >> 1;                 // 0..31
  const int bn = xcd * 2 + (local & 1);      // 0..15
  const int lane = t & 63, w = t >> 6;       // 4 waves, 2x2
  const int wr = w >> 1, wcn = w & 1;        // per-wave 64x64
  const int lr = lane & 15, lg = lane >> 4;

  int aoff[2], boff[2];
#pragma unroll
  for (int i = 0; i < 2; ++i) {
    int p = i*256 + t, ln = p >> 3, sr = (p & 7) ^ (ln & 7);
    aoff[i] = (2*ln + (sr >> 2)) * DD + (sr & 3) * 8;
    boff[i] = aoff[i];
  }
  const ushort* Ab = A  + (long)(bm*128) * DD;
  const ushort* Bb = Bt + (long)(bn*128) * DD;

#define STG_A(KT, BUF) do { const ushort* g_ = Ab + (KT)*32;               \
    ushort* l_ = lds + (BUF)*8192;                                         \
    gld_lds16(g_ + aoff[0], l_ + t*8);                                     \
    gld_lds16(g_ + aoff[1], l_ + (256 + t)*8); } while (0)
#define STG_B(KT, BUF) do { const ushort* g_ = Bb + (KT)*32;               \
    ushort* l_ = lds + (BUF)*8192 + 4096;                                  \
    gld_lds16(g_ + boff[0], l_ + t*8);                                     \
    gld_lds16(g_ + boff[1], l_ + (256 + t)*8); } while (0)
#define LDA(dst, m) { int r_ = wr*64 + (m)*16 + lr; int ln_ = r_ >> 1;     \
    int sl_ = (lg + ((r_ & 1) << 2)) ^ (ln_ & 7);                          \
    (dst) = *(const bf16x8*)(cb + ln_*128 + sl_*16); }
#define LDB(dst, n) { int r_ = wcn*64 + (n)*16 + lr; int ln_ = r_ >> 1;    \
    int sl_ = (lg + ((r_ & 1) << 2)) ^ (ln_ & 7);                          \
    (dst) = *(const bf16x8*)(cb + 8192 + ln_*128 + sl_*16); }
#define MFMA8(AV, BV, NB_) do {                                            \
    __builtin_amdgcn_s_setprio(1);                                         \
    _Pragma("unroll") for (int m = 0; m < 4; ++m)                          \
    _Pragma("unroll") for (int n = 0; n < 2; ++n)                          \
      acc[m][(NB_)+n] = __builtin_amdgcn_mfma_f32_16x16x32_bf16(           \
          AV[m], BV[n], acc[m][(NB_)+n], 0, 0, 0);                         \
    __builtin_amdgcn_s_setprio(0); } while (0)
#define SB  __builtin_amdgcn_sched_barrier(0)
#define BAR __builtin_amdgcn_s_barrier()
#define LGKM0 asm volatile("s_waitcnt lgkmcnt(0)" ::: "memory")

  f32x4 acc[4][4] = {};
  const int T = DD / 32;                     // 64 K-tiles

  STG_A(0, 0); STG_B(0, 0);
  STG_A(1, 1); STG_B(1, 1);
  asm volatile("s_waitcnt vmcnt(4)" ::: "memory");
  SB; BAR; SB;

  for (int kt = 0; kt < T; ++kt) {
    const char* cb = (const char*)lds + (kt % 3) * 16384;
    const int bs = (kt + 2) % 3;
    const bool st = (kt + 2 < T);
    bf16x8 a[4], b01[2], b23[2];
    LDA(a[0],0); LDA(a[1],1); LDA(a[2],2); LDA(a[3],3);
    LDB(b01[0],0); LDB(b01[1],1);
    if (st) STG_A(kt+2, bs);
    SB; BAR; LGKM0; SB;
    MFMA8(a, b01, 0);
    SB; BAR; SB;
    LDB(b23[0],2); LDB(b23[1],3);
    if (st) STG_B(kt+2, bs);
    SB; BAR; LGKM0; SB;
    MFMA8(a, b23, 2);
    SB;
    if (st)              { asm volatile("s_waitcnt vmcnt(4)" ::: "memory"); }
    else if (kt + 1 < T) { asm volatile("s_waitcnt vmcnt(0)" ::: "memory"); }
    SB; BAR; SB;
  }
#undef STG_A
#undef STG_B
#undef LDA
#undef LDB
#undef MFMA8
#undef SB
#undef BAR
#undef LGKM0

  const int crb = bm*128 + wr*64 + lg*4;
  const int ccb = bn*128 + wcn*64 + lr;
#pragma unroll
  for (int m = 0; m < 4; ++m)
#pragma unroll
    for (int n = 0; n < 4; ++n)
#pragma unroll
      for (int j = 0; j < 4; ++j)
        Cf[(long)(crb + m*16 + j) * DD + (ccb + n*16)] = acc[m][n][j];
}

// --- causal flash attn: KVBLK=128, dbuf, pair-balance, defer-max, MFMA-sum ---
// vs R18: the softmax row-sum shuffle chain (4 j x 4 shfl_xor) is replaced by
// an MFMA against an all-ones B fragment: accL = mfma(pa, ones, accL) sums
// the SAME bf16-quantized P the numerator uses (self-consistent denominator,
// masked entries contribute exp2(-inf)=0). accL rescales like accO on the
// defer-max trigger. Removes ~500 cyc of dependent cross-lane latency/tile.
__global__ __launch_bounds__(512, 2) void attn_fwd(
    const ushort* __restrict__ Qb, const ushort* __restrict__ Kb,
    const ushort* __restrict__ Vtg, ushort* __restrict__ Ob)
{
  __shared__ ushort Ks[2][128*128]; // 2 x 32 KB, [k][d] rows 256B swizzled
  __shared__ ushort Vs[2][128*128]; // 2 x 32 KB, [d][s] rows 256B swizzled
  __shared__ ushort Ps[8*16*68];    // per-wave P [16][64], pad 68 (2-way)

  const int bid = blockIdx.x;       // 256 blocks: p(8) x bh(32)
  const int p = bid >> 5;           // 0..7
  const int bh = bid & 31;
  const int b = bh >> 4, h = bh & 15;
  const int t = threadIdx.x;
  const int lane = t & 63;
  const int wq = t >> 6;            // 0..7
  const int lr = lane & 15, lg = lane >> 4;

  bf16x8 ones;                      // all-ones B fragment (layout-free)
#pragma unroll
  for (int i = 0; i < 8; ++i) ones[i] = (short)0x3F80;

  int koff[4], voff[4];
#pragma unroll
  for (int i = 0; i < 4; ++i) {
    int c = i*512 + t;
    int kr = c >> 4, kc = c & 15;
    koff[i] = kr*DD + ((kc ^ (kr & 7)) * 8);
    voff[i] = kr*SS + ((kc ^ (kr & 7)) * 8);
  }
  const ushort* Kg = Kb + (long)(b * SS) * DD + h * HDIM;
  const ushort* Vg = Vtg + (long)(bh * HDIM) * SS;

#define STAGE(KT, BUF) do {                                     \
    const ushort* kg_ = Kg + (long)(KT) * 128 * DD;             \
    const ushort* vg_ = Vg + (KT) * 128;                        \
    _Pragma("unroll") for (int i_ = 0; i_ < 4; ++i_) {          \
      gld_lds16(kg_ + koff[i_], &Ks[BUF][i_*4096 + t*8]);       \
      gld_lds16(vg_ + voff[i_], &Vs[BUF][i_*4096 + t*8]);       \
    } } while (0)

  ushort* myP = Ps + wq * (16*68);
  const int n0 = p + 1;             // half-0 tile count (128-key tiles)
  const int TOT = 17;               // n0 + (16 - p)

  STAGE(0, 0);
  __syncthreads();                  // tile 0 resident

  int u = 0;
  for (int half = 0; half < 2; ++half) {
    const int qt = half ? (15 - p) : p;
    const int qbase = qt * 128;
    const long rowQ = (long)(b * SS + qbase + wq * 16);
    const int ntile = qt + 1;
    const int qminw = qbase + wq*16;

    bf16x8 qf[4];
#pragma unroll
    for (int c = 0; c < 4; ++c)
      qf[c] = *(const bf16x8*)(Qb + (rowQ + lr) * DD + h*HDIM + c*32 + lg*8);

    f32x4 accO[8] = {};
    f32x4 accL = {};                // row-sum accumulator (denominator)
    float mrow[4];
#pragma unroll
    for (int j = 0; j < 4; ++j) mrow[j] = -1e30f;

    for (int kt = 0; kt < ntile; ++kt, ++u) {
      const int k0 = kt * 128;
      const int cur = u & 1;
      if (u + 1 < TOT) {
        const int un = u + 1;
        const int ktn = (un < n0) ? un : un - n0;
        STAGE(ktn, cur ^ 1);
      }

      const ushort* Kc = Ks[cur];
      const ushort* Vc = Vs[cur];
      f32x4 sc[8] = {};
      __builtin_amdgcn_s_setprio(1);
#pragma unroll
      for (int n = 0; n < 8; ++n) { // S = Q K^T : 16 q-rows x 128 keys
        int r = n*16 + lr;
        int swz = (r & 7) << 4;
#pragma unroll
        for (int c = 0; c < 4; ++c) {
          bf16x8 kf = *(const bf16x8*)((const char*)Kc + ((r*256 + c*64 + lg*16) ^ swz));
          sc[n] = __builtin_amdgcn_mfma_f32_16x16x32_bf16(qf[c], kf, sc[n], 0,0,0);
        }
      }
      __builtin_amdgcn_s_setprio(0);
      if (kt == ntile - 1) {        // diagonal 128-tile: causal mask
#pragma unroll
        for (int n = 0; n < 8; ++n)
#pragma unroll
          for (int j = 0; j < 4; ++j) {
            int kpos = k0 + n*16 + lr;
            int qpos = qminw + lg*4 + j;
            if (kpos > qpos) sc[n][j] = -1e30f;
          }
      }
      // tile max per row + defer-max decision (T13)
      float tm[4]; float gd = -1e30f;
#pragma unroll
      for (int j = 0; j < 4; ++j) {
        float m8 = fmaxf(fmaxf(fmaxf(sc[0][j], sc[1][j]), fmaxf(sc[2][j], sc[3][j])),
                         fmaxf(fmaxf(sc[4][j], sc[5][j]), fmaxf(sc[6][j], sc[7][j])));
#pragma unroll
        for (int off = 1; off < 16; off <<= 1) m8 = fmaxf(m8, __shfl_xor(m8, off));
        tm[j] = m8;
        gd = fmaxf(gd, m8 - mrow[j]);
      }
      const bool resc = !__all(gd <= 8.0f);
      if (resc) {
        float al[4];
#pragma unroll
        for (int j = 0; j < 4; ++j) {
          float mn = fmaxf(mrow[j], tm[j]);
          al[j] = fast_exp2(mrow[j] - mn);
          mrow[j] = mn;
        }
#pragma unroll
        for (int dg = 0; dg < 8; ++dg) {
          f32x4 v = accO[dg];
          v[0] *= al[0]; v[1] *= al[1]; v[2] *= al[2]; v[3] *= al[3];
          accO[dg] = v;
        }
        accL[0] *= al[0]; accL[1] *= al[1]; accL[2] *= al[2]; accL[3] *= al[3];
      }
#pragma unroll
      for (int j = 0; j < 4; ++j)   // P = exp2(S - mrow); no sum reduce
#pragma unroll
        for (int n = 0; n < 8; ++n)
          sc[n][j] = fast_exp2(sc[n][j] - mrow[j]);
      // PV in two 64-key halves (P buffer is 16x64 per wave)
#pragma unroll
      for (int hh = 0; hh < 2; ++hh) {
#pragma unroll
        for (int n2 = 0; n2 < 4; ++n2)
#pragma unroll
          for (int j = 0; j < 4; ++j)
            myP[(lg*4 + j)*68 + n2*16 + lr] = f2bf(sc[hh*4 + n2][j]);
        bf16x8 pa0 = *(const bf16x8*)(myP + lr*68 + lg*8);
        bf16x8 pa1 = *(const bf16x8*)(myP + lr*68 + 32 + lg*8);
        __builtin_amdgcn_s_setprio(1);
        accL = __builtin_amdgcn_mfma_f32_16x16x32_bf16(pa0, ones, accL, 0,0,0);
        accL = __builtin_amdgcn_mfma_f32_16x16x32_bf16(pa1, ones, accL, 0,0,0);
#pragma unroll
        for (int dg = 0; dg < 8; ++dg) { // O += P_half * V_half
          int d = dg*16 + lr;
          int vswz = (d & 7) << 4;
          bf16x8 v0 = *(const bf16x8*)((const char*)Vc + ((d*256 + hh*128 + lg*16) ^ vswz));
          bf16x8 v1 = *(const bf16x8*)((const char*)Vc + ((d*256 + hh*128 + 64 + lg*16) ^ vswz));
          accO[dg] = __builtin_amdgcn_mfma_f32_16x16x32_bf16(pa0, v0, accO[dg], 0,0,0);
          accO[dg] = __builtin_amdgcn_mfma_f32_16x16x32_bf16(pa1, v1, accO[dg], 0,0,0);
        }
        __builtin_amdgcn_s_setprio(0);
      }
      __syncthreads();              // drains next tile's loads (after compute)
    }

    float inv[4];
#pragma unroll
    for (int j = 0; j < 4; ++j) inv[j] = 1.0f / accL[j];
    ushort* Og = Ob + rowQ * DD + h * HDIM;
#pragma unroll
    for (int dg = 0; dg < 8; ++dg)
#pragma unroll
      for (int j = 0; j < 4; ++j)
        Og[(long)(lg*4 + j) * DD + dg*16 + lr] = f2bf(accO[dg][j] * inv[j]);
  }
#undef STAGE
}

// ---------------- launch ----------------------------------------------------
extern "C" void kernel_launch(void* const* d_in, const int* in_sizes, int n_in,
                              void* d_out, int out_size, void* d_ws, size_t ws_size,
                              hipStream_t stream) {
  const float* x  = (const float*)d_in[0];
  const float* Wq = (const float*)d_in[1];
  const float* Wk = (const float*)d_in[2];
  const float* Wv = (const float*)d_in[3];
  const float* Wo = (const float*)d_in[4];

  ushort* ws  = (ushort*)d_ws;
  ushort* xb  = ws;                         // x bf16; later reused as attn-out
  ushort* wqb = ws  + (long)MM*DD;          // wq/wk/wv contiguous = fused Bt
  ushort* wkb = wqb + (long)DD*DD;
  ushort* wvb = wkb + (long)DD*DD;
  ushort* wob = wvb + (long)DD*DD;
  ushort* Qb  = wob + (long)DD*DD;
  ushort* Kb  = Qb  + (long)MM*DD;
  ushort* Vtg = Kb  + (long)MM*DD;          // V stored transposed [bh*128+d][s]
  (void)wkb; (void)wvb;

  cvt_all<<<2048, 256, 0, stream>>>(x, Wq, Wk, Wv, Wo, ws);

  gemm_qkv<<<768, 256, 0, stream>>>(xb, wqb, Qb, Kb, Vtg);

  attn_fwd<<<256, 512, 0, stream>>>(Qb, Kb, Vtg, xb);   // attn out -> xb

  gemm_o128<<<512, 256, 0, stream>>>(xb, wob, (float*)d_out);
}